// Round 1
// baseline (4167.848 us; speedup 1.0000x reference)
//
#include <hip/hip_runtime.h>

#define B_   8
#define C_   256
#define R_   14
#define R2   196
#define N3   2744      // 14^3
#define NH   4
#define KD   16
#define DV   64
#define QKVO 96        // 2*KD + DV
#define MT   64        // m-tile in attention

__device__ __forceinline__ int iabs(int v){ return v < 0 ? -v : v; }

// ---------------------------------------------------------------------------
// QKV: y[o,n] = sum_c W[o,c] * feat[c,n]; feat = x_chunk (+ prev attn out)
// grid (ceil(N3/256), B), block 256
// ---------------------------------------------------------------------------
__global__ __launch_bounds__(256)
void qkv_kernel(const float* __restrict__ x, const float* __restrict__ h,
                const float* __restrict__ W, const float* __restrict__ sc,
                const float* __restrict__ bi,
                float* __restrict__ q0, float* __restrict__ kb, float* __restrict__ vb,
                int head)
{
    int b = blockIdx.y;
    int n = blockIdx.x * 256 + threadIdx.x;
    if (n >= N3) return;

    float f[64];
    const float* xb = x + ((size_t)b * C_ + head * DV) * N3 + n;
    if (head == 0) {
#pragma unroll
        for (int c = 0; c < 64; c++) f[c] = xb[(size_t)c * N3];
    } else {
        const float* hb = h + ((size_t)b * C_ + (head - 1) * DV) * N3 + n;
#pragma unroll
        for (int c = 0; c < 64; c++) f[c] = xb[(size_t)c * N3] + hb[(size_t)c * N3];
    }

    const float* Wh  = W  + head * QKVO * 64;   // uniform across threads -> s_loads
    const float* sch = sc + head * QKVO;
    const float* bih = bi + head * QKVO;

    float* qo = q0 + (size_t)b * KD * N3 + n;
    float* ko = kb + (size_t)b * KD * N3 + n;
    float* vo = vb + (size_t)b * DV * N3 + n;

    for (int o = 0; o < QKVO; o++) {
        float acc = 0.f;
#pragma unroll
        for (int c = 0; c < 64; c++) acc += Wh[o * 64 + c] * f[c];
        acc = acc * sch[o] + bih[o];
        if (o < KD)            qo[(size_t)o * N3] = acc;
        else if (o < 2 * KD)   ko[(size_t)(o - KD) * N3] = acc;
        else                   vo[(size_t)(o - 2 * KD) * N3] = acc;
    }
}

// ---------------------------------------------------------------------------
// Depthwise 5x5x5 SAME conv on q, in-place (reads LDS copy), + scale/bias
// grid (KD, B), block 256
// ---------------------------------------------------------------------------
__global__ __launch_bounds__(256)
void dwconv_kernel(float* __restrict__ q0, const float* __restrict__ Wdw,
                   const float* __restrict__ dsc, const float* __restrict__ dbi,
                   int head)
{
    __shared__ float ch[N3];
    int b = blockIdx.y, c = blockIdx.x;
    int t = threadIdx.x;
    float* qc = q0 + ((size_t)b * KD + c) * N3;
    for (int i = t; i < N3; i += 256) ch[i] = qc[i];
    __syncthreads();

    const float* w = Wdw + (head * KD + c) * 125;   // uniform -> s_loads
    float scl = dsc[head * KD + c], bia = dbi[head * KD + c];

    for (int i = t; i < N3; i += 256) {
        int xx = i / R2; int rem = i - xx * R2; int yy = rem / R_; int zz = rem - yy * R_;
        float acc = 0.f;
#pragma unroll
        for (int a = 0; a < 5; a++) {
            int xa = xx + a - 2;
            if ((unsigned)xa >= (unsigned)R_) continue;
#pragma unroll
            for (int bb = 0; bb < 5; bb++) {
                int yb = yy + bb - 2;
                if ((unsigned)yb >= (unsigned)R_) continue;
#pragma unroll
                for (int cc = 0; cc < 5; cc++) {
                    int zc = zz + cc - 2;
                    if ((unsigned)zc >= (unsigned)R_) continue;
                    acc += w[a * 25 + bb * 5 + cc] * ch[xa * R2 + yb * R_ + zc];
                }
            }
        }
        qc[i] = acc * scl + bia;
    }
}

// ---------------------------------------------------------------------------
// Fused attention: per block 64 q-rows; thread = (q-pair, m-slice of 8).
// Online softmax, analytic bias index. Writes h[b, head*64+c, n].
// grid (ceil(N3/64)=43, B), block 256
// ---------------------------------------------------------------------------
__global__ __launch_bounds__(256)
void attn_kernel(const float* __restrict__ qb, const float* __restrict__ kg0,
                 const float* __restrict__ vg0, float* __restrict__ h,
                 const float* __restrict__ abias, int head)
{
    __shared__ float kt[MT][20];     // [m][d], padded stride 20 (80B, 16B-aligned)
    __shared__ float vt[MT][68];     // [m][c], padded stride 68 (272B, 16B-aligned)
    __shared__ int   mxa[MT];
    __shared__ int   mya[MT];
    __shared__ float ab[R2];

    int b = blockIdx.y;
    int qbase = blockIdx.x * 64;
    int t = threadIdx.x;
    int s = t & 7;          // m-slice
    int p = t >> 3;         // q-pair index [0,32)
    int rA = qbase + p, rB = rA + 32;
    bool vA = rA < N3, vB = rB < N3;

    if (t < R2) ab[t] = abias[head * R2 + t];

    const float* qq = qb + (size_t)b * KD * N3;
    float qA[KD], qB[KD];
#pragma unroll
    for (int d = 0; d < KD; d++) {
        qA[d] = vA ? qq[(size_t)d * N3 + rA] : 0.f;
        qB[d] = vB ? qq[(size_t)d * N3 + rB] : 0.f;
    }
    int nxA = vA ? rA / R2 : 0; int nyA = vA ? (rA - nxA * R2) / R_ : 0;
    int nxB = vB ? rB / R2 : 0; int nyB = vB ? (rB - nxB * R2) / R_ : 0;

    float mA = -3.0e38f, lA = 0.f, mB = -3.0e38f, lB = 0.f;
    float4 aA[16], aB[16];
#pragma unroll
    for (int r = 0; r < 16; r++) { aA[r] = make_float4(0,0,0,0); aB[r] = make_float4(0,0,0,0); }

    const float* kg = kg0 + (size_t)b * KD * N3;
    const float* vg = vg0 + (size_t)b * DV * N3;

    for (int m0 = 0; m0 < N3; m0 += MT) {
        int mt = min(MT, N3 - m0);
        __syncthreads();
        for (int i = t; i < MT * KD; i += 256) {
            int mm = i & 63, d = i >> 6; int m = m0 + mm;
            kt[mm][d] = (m < N3) ? kg[(size_t)d * N3 + m] : 0.f;
        }
        for (int i = t; i < MT * DV; i += 256) {
            int mm = i & 63, c = i >> 6; int m = m0 + mm;
            vt[mm][c] = (m < N3) ? vg[(size_t)c * N3 + m] : 0.f;
        }
        if (t < MT) {
            int m = m0 + t;
            int mx = (m < N3) ? m / R2 : 0;
            int rem = m - mx * R2;
            mxa[t] = mx; mya[t] = (m < N3) ? rem / R_ : 0;
        }
        __syncthreads();

#pragma unroll
        for (int j = 0; j < 8; j++) {
            int mm = s + j * 8;
            if (mm >= mt) break;
            float kk[16];
            *(float4*)&kk[0]  = *(const float4*)&kt[mm][0];
            *(float4*)&kk[4]  = *(const float4*)&kt[mm][4];
            *(float4*)&kk[8]  = *(const float4*)&kt[mm][8];
            *(float4*)&kk[12] = *(const float4*)&kt[mm][12];
            float dA = 0.f, dB = 0.f;
#pragma unroll
            for (int d = 0; d < 16; d++) { dA += qA[d] * kk[d]; dB += qB[d] * kk[d]; }
            int mx = mxa[mm], my = mya[mm];
            float lgA = 0.25f * dA + ab[iabs(nxA - mx) * R_ + iabs(nyA - my)];
            float lgB = 0.25f * dB + ab[iabs(nxB - mx) * R_ + iabs(nyB - my)];
            float wA, wB;
            if (lgA <= mA) { wA = __expf(lgA - mA); lA += wA; }
            else {
                float fr = __expf(mA - lgA); lA = lA * fr + 1.f; mA = lgA; wA = 1.f;
#pragma unroll
                for (int r = 0; r < 16; r++) { aA[r].x *= fr; aA[r].y *= fr; aA[r].z *= fr; aA[r].w *= fr; }
            }
            if (lgB <= mB) { wB = __expf(lgB - mB); lB += wB; }
            else {
                float fr = __expf(mB - lgB); lB = lB * fr + 1.f; mB = lgB; wB = 1.f;
#pragma unroll
                for (int r = 0; r < 16; r++) { aB[r].x *= fr; aB[r].y *= fr; aB[r].z *= fr; aB[r].w *= fr; }
            }
#pragma unroll
            for (int r = 0; r < 16; r++) {
                float4 vv = *(const float4*)&vt[mm][r * 4];
                aA[r].x += wA * vv.x; aA[r].y += wA * vv.y; aA[r].z += wA * vv.z; aA[r].w += wA * vv.w;
                aB[r].x += wB * vv.x; aB[r].y += wB * vv.y; aB[r].z += wB * vv.z; aB[r].w += wB * vv.w;
            }
        }
    }

    // combine 8 m-slices (lanes differing in bits 0..2) via butterfly
#pragma unroll
    for (int mask = 1; mask < 8; mask <<= 1) {
        float moA = __shfl_xor(mA, mask); float loA = __shfl_xor(lA, mask);
        float nmA = fmaxf(mA, moA);
        float fsA = __expf(mA - nmA), foA = __expf(moA - nmA);
        lA = lA * fsA + loA * foA;
        float moB = __shfl_xor(mB, mask); float loB = __shfl_xor(lB, mask);
        float nmB = fmaxf(mB, moB);
        float fsB = __expf(mB - nmB), foB = __expf(moB - nmB);
        lB = lB * fsB + loB * foB;
#pragma unroll
        for (int r = 0; r < 16; r++) {
            float vx;
            vx = __shfl_xor(aA[r].x, mask); aA[r].x = aA[r].x * fsA + vx * foA;
            vx = __shfl_xor(aA[r].y, mask); aA[r].y = aA[r].y * fsA + vx * foA;
            vx = __shfl_xor(aA[r].z, mask); aA[r].z = aA[r].z * fsA + vx * foA;
            vx = __shfl_xor(aA[r].w, mask); aA[r].w = aA[r].w * fsA + vx * foA;
            vx = __shfl_xor(aB[r].x, mask); aB[r].x = aB[r].x * fsB + vx * foB;
            vx = __shfl_xor(aB[r].y, mask); aB[r].y = aB[r].y * fsB + vx * foB;
            vx = __shfl_xor(aB[r].z, mask); aB[r].z = aB[r].z * fsB + vx * foB;
            vx = __shfl_xor(aB[r].w, mask); aB[r].w = aB[r].w * fsB + vx * foB;
        }
        mA = nmA; mB = nmB;
    }

    float iA = 1.f / lA, iB = 1.f / lB;
    float* hb = h + ((size_t)b * C_ + head * DV) * N3;
#pragma unroll
    for (int r = 0; r < 16; r++) {
        if ((r >> 1) == s) {   // lane s owns r = 2s, 2s+1  -> 8 channels
            if (vA) {
                hb[(size_t)(r*4+0) * N3 + rA] = aA[r].x * iA;
                hb[(size_t)(r*4+1) * N3 + rA] = aA[r].y * iA;
                hb[(size_t)(r*4+2) * N3 + rA] = aA[r].z * iA;
                hb[(size_t)(r*4+3) * N3 + rA] = aA[r].w * iA;
            }
            if (vB) {
                hb[(size_t)(r*4+0) * N3 + rB] = aB[r].x * iB;
                hb[(size_t)(r*4+1) * N3 + rB] = aB[r].y * iB;
                hb[(size_t)(r*4+2) * N3 + rB] = aB[r].z * iB;
                hb[(size_t)(r*4+3) * N3 + rB] = aB[r].w * iB;
            }
        }
    }
}

// ---------------------------------------------------------------------------
// Projection: out[o,n] = psc[o]*sum_c Wp[o,c]*relu(h[c,n]) + pbi[o]
// grid (98, B), block 128; thread handles o=t and o=t+128 over 28 n's
// ---------------------------------------------------------------------------
__global__ __launch_bounds__(128)
void proj_kernel(const float* __restrict__ h, const float* __restrict__ Wp,
                 const float* __restrict__ psc, const float* __restrict__ pbi,
                 float* __restrict__ out)
{
    __shared__ float ht[256][28];
    int b = blockIdx.y; int n0 = blockIdx.x * 28; int t = threadIdx.x;

    const float* hb = h + (size_t)b * C_ * N3 + n0;
    for (int i = t; i < 256 * 28; i += 128) {
        int c = i / 28; int j = i - c * 28;
        float v = hb[(size_t)c * N3 + j];
        ht[c][j] = v > 0.f ? v : 0.f;
    }
    __syncthreads();

    int o0 = t, o1 = t + 128;
    float a0[28], a1[28];
#pragma unroll
    for (int j = 0; j < 28; j++) { a0[j] = 0.f; a1[j] = 0.f; }

    const float4* w04 = (const float4*)(Wp + (size_t)o0 * 256);
    const float4* w14 = (const float4*)(Wp + (size_t)o1 * 256);
    for (int c4 = 0; c4 < 64; c4++) {
        float4 wa = w04[c4], wb = w14[c4];
        int cb = c4 * 4;
#pragma unroll
        for (int u = 0; u < 4; u++) {
            float W0 = (u == 0) ? wa.x : (u == 1) ? wa.y : (u == 2) ? wa.z : wa.w;
            float W1 = (u == 0) ? wb.x : (u == 1) ? wb.y : (u == 2) ? wb.z : wb.w;
#pragma unroll
            for (int j = 0; j < 28; j++) {
                a0[j] += W0 * ht[cb + u][j];
                a1[j] += W1 * ht[cb + u][j];
            }
        }
    }

    float s0 = psc[o0], b0 = pbi[o0], s1 = psc[o1], b1 = pbi[o1];
    float* ob0 = out + ((size_t)b * C_ + o0) * N3 + n0;
    float* ob1 = out + ((size_t)b * C_ + o1) * N3 + n0;
#pragma unroll
    for (int j = 0; j < 28; j++) {
        ob0[j] = a0[j] * s0 + b0;
        ob1[j] = a1[j] * s1 + b1;
    }
}

// ---------------------------------------------------------------------------
extern "C" void kernel_launch(void* const* d_in, const int* in_sizes, int n_in,
                              void* d_out, int out_size, void* d_ws, size_t ws_size,
                              hipStream_t stream)
{
    const float* x    = (const float*)d_in[0];
    const float* Wqkv = (const float*)d_in[1];
    const float* qsc  = (const float*)d_in[2];
    const float* qbi  = (const float*)d_in[3];
    const float* Wdw  = (const float*)d_in[4];
    const float* dsc  = (const float*)d_in[5];
    const float* dbi  = (const float*)d_in[6];
    const float* Wp   = (const float*)d_in[7];
    const float* psc  = (const float*)d_in[8];
    const float* pbi  = (const float*)d_in[9];
    const float* ab   = (const float*)d_in[10];
    // d_in[11] = bias_idx: unused (computed analytically)

    float* out = (float*)d_out;
    float* ws  = (float*)d_ws;
    float* q0 = ws;                                   // B*KD*N3
    float* kb = q0 + (size_t)B_ * KD * N3;            // B*KD*N3
    float* vb = kb + (size_t)B_ * KD * N3;            // B*DV*N3
    float* h  = vb + (size_t)B_ * DV * N3;            // B*C_*N3 (pre-relu)

    for (int head = 0; head < NH; head++) {
        qkv_kernel<<<dim3(11, B_), 256, 0, stream>>>(x, h, Wqkv, qsc, qbi, q0, kb, vb, head);
        dwconv_kernel<<<dim3(KD, B_), 256, 0, stream>>>(q0, Wdw, dsc, dbi, head);
        attn_kernel<<<dim3(43, B_), 256, 0, stream>>>(q0, kb, vb, h, ab, head);
    }
    proj_kernel<<<dim3(98, B_), 128, 0, stream>>>(h, Wp, psc, pbi, out);
}